// Round 4
// baseline (389.275 us; speedup 1.0000x reference)
//
#include <hip/hip_runtime.h>
#include <hip/hip_fp16.h>
#include <math.h>

#define H 4
#define HD 16
#define NEG_SLOPE 0.2f
#define EPS_SM 1e-8f
#define EPS_LN 1e-5f

// ---------------------------------------------------------------------------
// Kernel 1: h = x @ W_node (64x64). 16 rows per 256-thread block; W in LDS.
// ---------------------------------------------------------------------------
__global__ __launch_bounds__(256) void k_node(
    const float* __restrict__ x, const float* __restrict__ Wn,
    float* __restrict__ h, int n)
{
    __shared__ float Ws[64][64];
    __shared__ float xs[16][64];
    const int tid = threadIdx.x;
    const int row0 = blockIdx.x * 16;

    for (int i = tid; i < 64 * 64; i += 256) Ws[i >> 6][i & 63] = Wn[i];
    for (int i = tid; i < 16 * 64; i += 256) {
        int r = row0 + (i >> 6);
        xs[i >> 6][i & 63] = (r < n) ? x[(size_t)r * 64 + (i & 63)] : 0.f;
    }
    __syncthreads();

    const int col = tid & 63;
    const int r0  = tid >> 6;   // 0..3
    float a0 = 0.f, a1 = 0.f, a2 = 0.f, a3 = 0.f;
    #pragma unroll
    for (int k = 0; k < 64; ++k) {
        float w = Ws[k][col];
        a0 += xs[r0     ][k] * w;
        a1 += xs[r0 +  4][k] * w;
        a2 += xs[r0 +  8][k] * w;
        a3 += xs[r0 + 12][k] * w;
    }
    float av[4] = {a0, a1, a2, a3};
    #pragma unroll
    for (int j = 0; j < 4; ++j) {
        int r = row0 + r0 + 4 * j;
        if (r < n) h[(size_t)r * 64 + col] = av[j];
    }
}

// ---------------------------------------------------------------------------
// Kernel 2: degree histogram over dst.
// ---------------------------------------------------------------------------
__global__ __launch_bounds__(256) void k_hist(
    const int* __restrict__ dst, int* __restrict__ deg, int E)
{
    int e = blockIdx.x * 256 + threadIdx.x;
    if (e < E) atomicAdd(&deg[dst[e]], 1);
}

// ---------------------------------------------------------------------------
// Scan: exclusive prefix sum of deg[n] -> row_start[n] (+ cursor copy).
// ---------------------------------------------------------------------------
__global__ __launch_bounds__(256) void k_scan_reduce(
    const int* __restrict__ deg, int* __restrict__ partials, int n)
{
    const int t = threadIdx.x;
    int idx = blockIdx.x * 1024 + t * 4;
    int s = 0;
    #pragma unroll
    for (int k = 0; k < 4; ++k) { int i = idx + k; if (i < n) s += deg[i]; }
    #pragma unroll
    for (int off = 32; off; off >>= 1) s += __shfl_xor(s, off, 64);
    __shared__ int wsum[4];
    if ((t & 63) == 0) wsum[t >> 6] = s;
    __syncthreads();
    if (t == 0) partials[blockIdx.x] = wsum[0] + wsum[1] + wsum[2] + wsum[3];
}

__global__ void k_scan_partials(int* __restrict__ partials, int nb)
{
    int lane = threadIdx.x;
    int i0 = 2 * lane, i1 = 2 * lane + 1;
    int v0 = (i0 < nb) ? partials[i0] : 0;
    int v1 = (i1 < nb) ? partials[i1] : 0;
    int s = v0 + v1;
    int incl = s;
    #pragma unroll
    for (int off = 1; off < 64; off <<= 1) {
        int u = __shfl_up(incl, off, 64);
        if (lane >= off) incl += u;
    }
    int excl = incl - s;
    if (i0 < nb) partials[i0] = excl;
    if (i1 < nb) partials[i1] = excl + v0;
}

__global__ __launch_bounds__(256) void k_scan_final(
    const int* __restrict__ deg, const int* __restrict__ partials,
    int* __restrict__ row_start, int* __restrict__ cursor, int n)
{
    const int t = threadIdx.x;
    const int lane = t & 63, wid = t >> 6;
    int idx = blockIdx.x * 1024 + t * 4;
    int d0 = (idx     < n) ? deg[idx    ] : 0;
    int d1 = (idx + 1 < n) ? deg[idx + 1] : 0;
    int d2 = (idx + 2 < n) ? deg[idx + 2] : 0;
    int d3 = (idx + 3 < n) ? deg[idx + 3] : 0;
    int s = d0 + d1 + d2 + d3;
    int incl = s;
    #pragma unroll
    for (int off = 1; off < 64; off <<= 1) {
        int u = __shfl_up(incl, off, 64);
        if (lane >= off) incl += u;
    }
    __shared__ int wsum[4];
    if (lane == 63) wsum[wid] = incl;
    __syncthreads();
    int woff = 0;
    for (int i = 0; i < wid; ++i) woff += wsum[i];
    int p = partials[blockIdx.x] + woff + (incl - s);
    if (idx     < n) { row_start[idx    ] = p; cursor[idx    ] = p; } p += d0;
    if (idx + 1 < n) { row_start[idx + 1] = p; cursor[idx + 1] = p; } p += d1;
    if (idx + 2 < n) { row_start[idx + 2] = p; cursor[idx + 2] = p; } p += d2;
    if (idx + 3 < n) { row_start[idx + 3] = p; cursor[idx + 3] = p; }
}

// ---------------------------------------------------------------------------
// Kernel 3: CSR build with packed payload.
// Record: int4 { src, f16x2(esc0,esc1), f16x2(esc2,esc3), 0 }.
// All reads coalesced; per edge only {atomic, one 16B scattered store}.
// ---------------------------------------------------------------------------
__global__ __launch_bounds__(256) void k_perm_build(
    const int* __restrict__ src, const int* __restrict__ dst,
    const float* __restrict__ ea, const float* __restrict__ We,
    int* __restrict__ cursor, int4* __restrict__ csr, int E)
{
    __shared__ float Wes[64];   // W_edge [16][4]
    const int tid = threadIdx.x;
    if (tid < 64) Wes[tid] = We[tid];
    __syncthreads();

    int e = blockIdx.x * 256 + tid;
    if (e >= E) return;

    int s = src[e];
    int d = dst[e];

    const float4* ea4 = (const float4*)(ea + (size_t)e * 16);
    float4 v0 = ea4[0], v1 = ea4[1], v2 = ea4[2], v3 = ea4[3];
    float eav[16] = {v0.x, v0.y, v0.z, v0.w, v1.x, v1.y, v1.z, v1.w,
                     v2.x, v2.y, v2.z, v2.w, v3.x, v3.y, v3.z, v3.w};
    float esc[H] = {0.f, 0.f, 0.f, 0.f};
    #pragma unroll
    for (int k = 0; k < 16; ++k) {
        #pragma unroll
        for (int hh = 0; hh < H; ++hh) esc[hh] += eav[k] * Wes[k * 4 + hh];
    }

    __half2 p01 = __floats2half2_rn(esc[0], esc[1]);
    __half2 p23 = __floats2half2_rn(esc[2], esc[3]);
    int y = *reinterpret_cast<int*>(&p01);
    int z = *reinterpret_cast<int*>(&p23);

    int pos = atomicAdd(&cursor[d], 1);
    csr[pos] = make_int4(s, y, z, 0);
}

// ---------------------------------------------------------------------------
// Kernel 4: wave-per-node single-pass online-softmax aggregation + residual +
// LayerNorm. lane = column (head = lane/16). a_dst from own h row (once),
// a_src[s] from the gathered h[s] row via 16-lane shfl reduce. No attn array,
// no max pre-pass. 4x unrolled so 4 h-gathers are in flight.
// ---------------------------------------------------------------------------
__global__ __launch_bounds__(256) void k_aggregate_ln(
    const int* __restrict__ row_start, const int* __restrict__ deg,
    const int4* __restrict__ csr, const float* __restrict__ h,
    const float* __restrict__ asrcW, const float* __restrict__ adstW,
    const float* __restrict__ gamma, const float* __restrict__ beta,
    float* __restrict__ out, int n)
{
    int gid  = blockIdx.x * 256 + threadIdx.x;
    int node = gid >> 6;
    int lane = gid & 63;
    if (node >= n) return;
    const int hh   = lane >> 4;
    const int hilo = lane >> 4 & 1;    // hh&1
    const float asw = asrcW[lane];     // attn_src[4][16] flat == lane order
    const float adw = adstW[lane];

    const int rs = row_start[node];
    const int dg = deg[node];

    const float h_node = h[(size_t)node * 64 + lane];

    // a_dst for this node (per-head, broadcast within 16-lane group)
    float ad = h_node * adw;
    #pragma unroll
    for (int off = 1; off < 16; off <<= 1) ad += __shfl_xor(ad, off, 64);

    float m = 0.f;        // include_self: max seeded with 0
    float sum = 0.f, accv = 0.f;

#define PROC_EDGE(HV, YW, ZW)                                            \
    {                                                                    \
        float as_ = (HV) * asw;                                          \
        as_ += __shfl_xor(as_, 1, 64);  as_ += __shfl_xor(as_, 2, 64);   \
        as_ += __shfl_xor(as_, 4, 64);  as_ += __shfl_xor(as_, 8, 64);   \
        int w_ = (hh < 2) ? (YW) : (ZW);                                 \
        float2 f2_ = __half22float2(*reinterpret_cast<__half2*>(&w_));   \
        float a_ = as_ + ad + (hilo ? f2_.y : f2_.x);                    \
        a_ = (a_ >= 0.f) ? a_ : NEG_SLOPE * a_;                          \
        float mn_ = fmaxf(m, a_);                                        \
        float sc_ = __expf(m - mn_);                                     \
        float w2_ = __expf(a_ - mn_);                                    \
        sum  = sum * sc_ + w2_;                                          \
        accv = accv * sc_ + w2_ * (HV);                                  \
        m = mn_;                                                         \
    }

    for (int base = 0; base < dg; base += 64) {
        int cnt = min(64, dg - base);
        int4 myc = (base + lane < dg) ? csr[(size_t)rs + base + lane]
                                      : make_int4(0, 0, 0, 0);
        int i = 0;
        for (; i + 4 <= cnt; i += 4) {
            int s0 = __shfl(myc.x, i + 0, 64);
            int s1 = __shfl(myc.x, i + 1, 64);
            int s2 = __shfl(myc.x, i + 2, 64);
            int s3 = __shfl(myc.x, i + 3, 64);
            int y0 = __shfl(myc.y, i + 0, 64), z0 = __shfl(myc.z, i + 0, 64);
            int y1 = __shfl(myc.y, i + 1, 64), z1 = __shfl(myc.z, i + 1, 64);
            int y2 = __shfl(myc.y, i + 2, 64), z2 = __shfl(myc.z, i + 2, 64);
            int y3 = __shfl(myc.y, i + 3, 64), z3 = __shfl(myc.z, i + 3, 64);
            float hv0 = h[(size_t)s0 * 64 + lane];
            float hv1 = h[(size_t)s1 * 64 + lane];
            float hv2 = h[(size_t)s2 * 64 + lane];
            float hv3 = h[(size_t)s3 * 64 + lane];
            PROC_EDGE(hv0, y0, z0);
            PROC_EDGE(hv1, y1, z1);
            PROC_EDGE(hv2, y2, z2);
            PROC_EDGE(hv3, y3, z3);
        }
        for (; i < cnt; ++i) {
            int s0 = __shfl(myc.x, i, 64);
            int y0 = __shfl(myc.y, i, 64);
            int z0 = __shfl(myc.z, i, 64);
            float hv0 = h[(size_t)s0 * 64 + lane];
            PROC_EDGE(hv0, y0, z0);
        }
    }
#undef PROC_EDGE

    float y = accv / (sum + EPS_SM) + h_node;

    // LayerNorm across the 64 lanes
    float t1 = y;
    #pragma unroll
    for (int off = 32; off; off >>= 1) t1 += __shfl_xor(t1, off, 64);
    float mu = t1 * (1.f / 64.f);
    float dv = y - mu;
    float vs = dv * dv;
    #pragma unroll
    for (int off = 32; off; off >>= 1) vs += __shfl_xor(vs, off, 64);
    float var = vs * (1.f / 64.f);
    out[(size_t)node * 64 + lane] = dv * rsqrtf(var + EPS_LN) * gamma[lane] + beta[lane];
}

// ---------------------------------------------------------------------------
extern "C" void kernel_launch(void* const* d_in, const int* in_sizes, int n_in,
                              void* d_out, int out_size, void* d_ws, size_t ws_size,
                              hipStream_t stream)
{
    const float* x     = (const float*)d_in[0];
    const int*   ei    = (const int*)  d_in[1];
    const float* ea    = (const float*)d_in[2];
    const float* Wn    = (const float*)d_in[3];
    const float* We    = (const float*)d_in[4];
    const float* asrcW = (const float*)d_in[5];
    const float* adstW = (const float*)d_in[6];
    const float* gamma = (const float*)d_in[7];
    const float* beta  = (const float*)d_in[8];
    float* out = (float*)d_out;

    const int n = in_sizes[0] / 64;
    const int E = in_sizes[1] / 2;
    const int* src = ei;
    const int* dst = ei + E;
    const int nb = (n + 1023) / 1024;

    float* ws = (float*)d_ws;
    size_t off = 0;
    float* h_  = ws + off; off += (size_t)n * 64;       // 16B-aligned
    int4* csr  = (int4*)(ws + off); off += (size_t)E * 4;
    int* ibase     = (int*)(ws + off);
    int* deg       = ibase;                   // n
    int* row_start = ibase + n;               // n
    int* cursor    = ibase + 2 * (size_t)n;   // n
    int* partials  = ibase + 3 * (size_t)n;   // nb

    hipMemsetAsync(deg, 0, (size_t)n * sizeof(int), stream);

    k_node<<<(n + 15) / 16, 256, 0, stream>>>(x, Wn, h_, n);
    k_hist<<<(E + 255) / 256, 256, 0, stream>>>(dst, deg, E);
    k_scan_reduce<<<nb, 256, 0, stream>>>(deg, partials, n);
    k_scan_partials<<<1, 64, 0, stream>>>(partials, nb);
    k_scan_final<<<nb, 256, 0, stream>>>(deg, partials, row_start, cursor, n);
    k_perm_build<<<(E + 255) / 256, 256, 0, stream>>>(src, dst, ea, We, cursor, csr, E);
    k_aggregate_ln<<<((size_t)n * 64 + 255) / 256, 256, 0, stream>>>(
        row_start, deg, csr, h_, asrcW, adstW, gamma, beta, out, n);
}

// Round 5
// 317.123 us; speedup vs baseline: 1.2275x; 1.2275x over previous
//
#include <hip/hip_runtime.h>
#include <hip/hip_fp16.h>
#include <math.h>

#define H 4
#define HD 16
#define NEG_SLOPE 0.2f
#define EPS_SM 1e-8f
#define EPS_LN 1e-5f
#define PAD 16   // one counter per 64B cache line

// ---------------------------------------------------------------------------
// Kernel 1: h = x @ W_node (64x64) + fused a_src/a_dst projections.
// 16 rows per 256-thread block; W in LDS.
// ---------------------------------------------------------------------------
__global__ __launch_bounds__(256) void k_node(
    const float* __restrict__ x, const float* __restrict__ Wn,
    const float* __restrict__ attn_src, const float* __restrict__ attn_dst,
    float* __restrict__ h, float* __restrict__ a_src, float* __restrict__ a_dst,
    int n)
{
    __shared__ float Ws[64][64];
    __shared__ float xs[16][64];
    __shared__ float hs[16][64];
    const int tid = threadIdx.x;
    const int row0 = blockIdx.x * 16;

    for (int i = tid; i < 64 * 64; i += 256) Ws[i >> 6][i & 63] = Wn[i];
    for (int i = tid; i < 16 * 64; i += 256) {
        int r = row0 + (i >> 6);
        xs[i >> 6][i & 63] = (r < n) ? x[(size_t)r * 64 + (i & 63)] : 0.f;
    }
    __syncthreads();

    const int col = tid & 63;
    const int r0  = tid >> 6;   // 0..3
    float a0 = 0.f, a1 = 0.f, a2 = 0.f, a3 = 0.f;
    #pragma unroll
    for (int k = 0; k < 64; ++k) {
        float w = Ws[k][col];
        a0 += xs[r0     ][k] * w;
        a1 += xs[r0 +  4][k] * w;
        a2 += xs[r0 +  8][k] * w;
        a3 += xs[r0 + 12][k] * w;
    }
    float av[4] = {a0, a1, a2, a3};
    #pragma unroll
    for (int j = 0; j < 4; ++j) {
        int rl = r0 + 4 * j;
        int r  = row0 + rl;
        hs[rl][col] = av[j];
        if (r < n) h[(size_t)r * 64 + col] = av[j];
    }
    __syncthreads();

    if (tid < 64) {
        int rl = tid >> 2;   // 0..15
        int hh = tid & 3;    // 0..3
        float s1 = 0.f, s2 = 0.f;
        #pragma unroll
        for (int d = 0; d < HD; ++d) {
            float v = hs[rl][hh * HD + d];
            s1 += v * attn_src[hh * HD + d];
            s2 += v * attn_dst[hh * HD + d];
        }
        int r = row0 + rl;
        if (r < n) {
            a_src[(size_t)r * 4 + hh] = s1;
            a_dst[(size_t)r * 4 + hh] = s2;
        }
    }
}

// ---------------------------------------------------------------------------
// Kernel 2: degree histogram over dst (padded counters, 1 per 64B line).
// ---------------------------------------------------------------------------
__global__ __launch_bounds__(256) void k_hist(
    const int* __restrict__ dst, int* __restrict__ degp, int E)
{
    int e = blockIdx.x * 256 + threadIdx.x;
    if (e < E) atomicAdd(&degp[(size_t)dst[e] * PAD], 1);
}

// ---------------------------------------------------------------------------
// Scan: exclusive prefix sum of degp (strided) -> row_start (dense) +
// cursorp (strided copy).
// ---------------------------------------------------------------------------
__global__ __launch_bounds__(256) void k_scan_reduce(
    const int* __restrict__ degp, int* __restrict__ partials, int n)
{
    const int t = threadIdx.x;
    int idx = blockIdx.x * 1024 + t * 4;
    int s = 0;
    #pragma unroll
    for (int k = 0; k < 4; ++k) { int i = idx + k; if (i < n) s += degp[(size_t)i * PAD]; }
    #pragma unroll
    for (int off = 32; off; off >>= 1) s += __shfl_xor(s, off, 64);
    __shared__ int wsum[4];
    if ((t & 63) == 0) wsum[t >> 6] = s;
    __syncthreads();
    if (t == 0) partials[blockIdx.x] = wsum[0] + wsum[1] + wsum[2] + wsum[3];
}

__global__ void k_scan_partials(int* __restrict__ partials, int nb)
{
    int lane = threadIdx.x;
    int i0 = 2 * lane, i1 = 2 * lane + 1;
    int v0 = (i0 < nb) ? partials[i0] : 0;
    int v1 = (i1 < nb) ? partials[i1] : 0;
    int s = v0 + v1;
    int incl = s;
    #pragma unroll
    for (int off = 1; off < 64; off <<= 1) {
        int u = __shfl_up(incl, off, 64);
        if (lane >= off) incl += u;
    }
    int excl = incl - s;
    if (i0 < nb) partials[i0] = excl;
    if (i1 < nb) partials[i1] = excl + v0;
}

__global__ __launch_bounds__(256) void k_scan_final(
    const int* __restrict__ degp, const int* __restrict__ partials,
    int* __restrict__ row_start, int* __restrict__ cursorp, int n)
{
    const int t = threadIdx.x;
    const int lane = t & 63, wid = t >> 6;
    int idx = blockIdx.x * 1024 + t * 4;
    int d0 = (idx     < n) ? degp[(size_t)(idx    ) * PAD] : 0;
    int d1 = (idx + 1 < n) ? degp[(size_t)(idx + 1) * PAD] : 0;
    int d2 = (idx + 2 < n) ? degp[(size_t)(idx + 2) * PAD] : 0;
    int d3 = (idx + 3 < n) ? degp[(size_t)(idx + 3) * PAD] : 0;
    int s = d0 + d1 + d2 + d3;
    int incl = s;
    #pragma unroll
    for (int off = 1; off < 64; off <<= 1) {
        int u = __shfl_up(incl, off, 64);
        if (lane >= off) incl += u;
    }
    __shared__ int wsum[4];
    if (lane == 63) wsum[wid] = incl;
    __syncthreads();
    int woff = 0;
    for (int i = 0; i < wid; ++i) woff += wsum[i];
    int p = partials[blockIdx.x] + woff + (incl - s);
    if (idx     < n) { row_start[idx    ] = p; cursorp[(size_t)(idx    ) * PAD] = p; } p += d0;
    if (idx + 1 < n) { row_start[idx + 1] = p; cursorp[(size_t)(idx + 1) * PAD] = p; } p += d1;
    if (idx + 2 < n) { row_start[idx + 2] = p; cursorp[(size_t)(idx + 2) * PAD] = p; } p += d2;
    if (idx + 3 < n) { row_start[idx + 3] = p; cursorp[(size_t)(idx + 3) * PAD] = p; }
}

// ---------------------------------------------------------------------------
// Kernel 3: CSR build. Record: int4 { src, f16x2(as0+esc0, as1+esc1),
// f16x2(as2+esc2, as3+esc3), 0 }. Atomic issued FIRST (latency overlapped
// with a_src gather + esc math); padded cursor kills line contention.
// ---------------------------------------------------------------------------
__global__ __launch_bounds__(256) void k_perm_build(
    const int* __restrict__ src, const int* __restrict__ dst,
    const float* __restrict__ ea, const float* __restrict__ We,
    const float* __restrict__ a_src,
    int* __restrict__ cursorp, int4* __restrict__ csr, int E)
{
    __shared__ float Wes[64];   // W_edge [16][4]
    const int tid = threadIdx.x;
    if (tid < 64) Wes[tid] = We[tid];
    __syncthreads();

    int e = blockIdx.x * 256 + tid;
    if (e >= E) return;

    int d = dst[e];
    int pos = atomicAdd(&cursorp[(size_t)d * PAD], 1);   // issue early
    int s = src[e];
    float4 as4 = *(const float4*)(a_src + (size_t)s * 4); // L2-resident gather

    const float4* ea4 = (const float4*)(ea + (size_t)e * 16);
    float4 v0 = ea4[0], v1 = ea4[1], v2 = ea4[2], v3 = ea4[3];
    float eav[16] = {v0.x, v0.y, v0.z, v0.w, v1.x, v1.y, v1.z, v1.w,
                     v2.x, v2.y, v2.z, v2.w, v3.x, v3.y, v3.z, v3.w};
    float esc[H] = {0.f, 0.f, 0.f, 0.f};
    #pragma unroll
    for (int k = 0; k < 16; ++k) {
        #pragma unroll
        for (int hh = 0; hh < H; ++hh) esc[hh] += eav[k] * Wes[k * 4 + hh];
    }

    __half2 p01 = __floats2half2_rn(as4.x + esc[0], as4.y + esc[1]);
    __half2 p23 = __floats2half2_rn(as4.z + esc[2], as4.w + esc[3]);
    int y = *reinterpret_cast<int*>(&p01);
    int z = *reinterpret_cast<int*>(&p23);

    csr[pos] = make_int4(s, y, z, 0);
}

// ---------------------------------------------------------------------------
// Kernel 4: wave-per-node aggregation + residual + LayerNorm.
// Record holds a_src[s]+esc; a_dst read once per node. No max tracking
// (exp(a) directly — differs from reference by <=1e-8 relative, see notes).
// Per edge: 3 shfl broadcasts + add + lrelu + exp + 2 fma + coalesced gather.
// ---------------------------------------------------------------------------
__global__ __launch_bounds__(256) void k_aggregate_ln(
    const int* __restrict__ row_start, const int* __restrict__ degp,
    const int4* __restrict__ csr, const float* __restrict__ h,
    const float* __restrict__ a_dst,
    const float* __restrict__ gamma, const float* __restrict__ beta,
    float* __restrict__ out, int n)
{
    int gid  = blockIdx.x * 256 + threadIdx.x;
    int node = gid >> 6;
    int lane = gid & 63;
    if (node >= n) return;
    const int hh   = lane >> 4;
    const int hilo = hh & 1;

    const int rs = row_start[node];
    const int dg = degp[(size_t)node * PAD];

    const float h_node = h[(size_t)node * 64 + lane];
    float4 ad4 = *(const float4*)(a_dst + (size_t)node * 4);
    const float ad = (hh == 0) ? ad4.x : (hh == 1) ? ad4.y : (hh == 2) ? ad4.z : ad4.w;

    float sum = 0.f, accv = 0.f;

#define PROC_EDGE(HV, YW, ZW)                                            \
    {                                                                    \
        int w_ = (hh < 2) ? (YW) : (ZW);                                 \
        float2 f2_ = __half22float2(*reinterpret_cast<__half2*>(&w_));   \
        float a_ = (hilo ? f2_.y : f2_.x) + ad;                          \
        a_ = (a_ >= 0.f) ? a_ : NEG_SLOPE * a_;                          \
        float w2_ = __expf(a_);                                          \
        sum  += w2_;                                                     \
        accv += w2_ * (HV);                                              \
    }

    for (int base = 0; base < dg; base += 64) {
        int cnt = min(64, dg - base);
        int4 myc = (base + lane < dg) ? csr[(size_t)rs + base + lane]
                                      : make_int4(0, 0, 0, 0);
        int i = 0;
        for (; i + 4 <= cnt; i += 4) {
            int s0 = __shfl(myc.x, i + 0, 64);
            int s1 = __shfl(myc.x, i + 1, 64);
            int s2 = __shfl(myc.x, i + 2, 64);
            int s3 = __shfl(myc.x, i + 3, 64);
            int y0 = __shfl(myc.y, i + 0, 64), z0 = __shfl(myc.z, i + 0, 64);
            int y1 = __shfl(myc.y, i + 1, 64), z1 = __shfl(myc.z, i + 1, 64);
            int y2 = __shfl(myc.y, i + 2, 64), z2 = __shfl(myc.z, i + 2, 64);
            int y3 = __shfl(myc.y, i + 3, 64), z3 = __shfl(myc.z, i + 3, 64);
            float hv0 = h[(size_t)s0 * 64 + lane];
            float hv1 = h[(size_t)s1 * 64 + lane];
            float hv2 = h[(size_t)s2 * 64 + lane];
            float hv3 = h[(size_t)s3 * 64 + lane];
            PROC_EDGE(hv0, y0, z0);
            PROC_EDGE(hv1, y1, z1);
            PROC_EDGE(hv2, y2, z2);
            PROC_EDGE(hv3, y3, z3);
        }
        for (; i < cnt; ++i) {
            int s0 = __shfl(myc.x, i, 64);
            int y0 = __shfl(myc.y, i, 64);
            int z0 = __shfl(myc.z, i, 64);
            float hv0 = h[(size_t)s0 * 64 + lane];
            PROC_EDGE(hv0, y0, z0);
        }
    }
#undef PROC_EDGE

    float y = accv / (sum + EPS_SM) + h_node;

    // LayerNorm across the 64 lanes
    float t1 = y;
    #pragma unroll
    for (int off = 32; off; off >>= 1) t1 += __shfl_xor(t1, off, 64);
    float mu = t1 * (1.f / 64.f);
    float dv = y - mu;
    float vs = dv * dv;
    #pragma unroll
    for (int off = 32; off; off >>= 1) vs += __shfl_xor(vs, off, 64);
    float var = vs * (1.f / 64.f);
    out[(size_t)node * 64 + lane] = dv * rsqrtf(var + EPS_LN) * gamma[lane] + beta[lane];
}

// ---------------------------------------------------------------------------
extern "C" void kernel_launch(void* const* d_in, const int* in_sizes, int n_in,
                              void* d_out, int out_size, void* d_ws, size_t ws_size,
                              hipStream_t stream)
{
    const float* x     = (const float*)d_in[0];
    const int*   ei    = (const int*)  d_in[1];
    const float* ea    = (const float*)d_in[2];
    const float* Wn    = (const float*)d_in[3];
    const float* We    = (const float*)d_in[4];
    const float* asrcW = (const float*)d_in[5];
    const float* adstW = (const float*)d_in[6];
    const float* gamma = (const float*)d_in[7];
    const float* beta  = (const float*)d_in[8];
    float* out = (float*)d_out;

    const int n = in_sizes[0] / 64;
    const int E = in_sizes[1] / 2;
    const int* src = ei;
    const int* dst = ei + E;
    const int nb = (n + 1023) / 1024;

    float* ws = (float*)d_ws;
    size_t off = 0;
    float* h_    = ws + off; off += (size_t)n * 64;      // 16B-aligned
    float* a_src = ws + off; off += (size_t)n * 4;
    float* a_dst = ws + off; off += (size_t)n * 4;
    int4* csr    = (int4*)(ws + off); off += (size_t)E * 4;
    int* ibase     = (int*)(ws + off);
    int* degp      = ibase;                          // n*PAD
    int* cursorp   = ibase + (size_t)n * PAD;        // n*PAD
    int* row_start = ibase + 2 * (size_t)n * PAD;    // n
    int* partials  = ibase + 2 * (size_t)n * PAD + n; // nb

    hipMemsetAsync(degp, 0, (size_t)n * PAD * sizeof(int), stream);

    k_node<<<(n + 15) / 16, 256, 0, stream>>>(x, Wn, asrcW, adstW, h_, a_src, a_dst, n);
    k_hist<<<(E + 255) / 256, 256, 0, stream>>>(dst, degp, E);
    k_scan_reduce<<<nb, 256, 0, stream>>>(degp, partials, n);
    k_scan_partials<<<1, 64, 0, stream>>>(partials, nb);
    k_scan_final<<<nb, 256, 0, stream>>>(degp, partials, row_start, cursorp, n);
    k_perm_build<<<(E + 255) / 256, 256, 0, stream>>>(src, dst, ea, We, a_src,
                                                      cursorp, csr, E);
    k_aggregate_ln<<<((size_t)n * 64 + 255) / 256, 256, 0, stream>>>(
        row_start, degp, csr, h_, a_dst, gamma, beta, out, n);
}

// Round 6
// 248.234 us; speedup vs baseline: 1.5682x; 1.2775x over previous
//
#include <hip/hip_runtime.h>
#include <hip/hip_fp16.h>
#include <math.h>

#define H 4
#define HD 16
#define NEG_SLOPE 0.2f
#define EPS_SM 1e-8f
#define EPS_LN 1e-5f
#define PAD 16   // one counter per 64B cache line

// ---------------------------------------------------------------------------
// Kernel 1: h = x @ W_node (64x64) + fused a_src/a_dst projections.
// 64 rows per 256-thread block. Register-tiled: each thread computes a
// 4-row x 4-col tile (cols 4*c4..4*c4+3, rows r4+{0,16,32,48}).
// All staging float4. Epilogue: per-row 4-fma dot + 2x shfl_xor reduce
// within the 4 threads of each head (lane strides 1,2) — all lanes busy.
// ---------------------------------------------------------------------------
__global__ __launch_bounds__(256) void k_node(
    const float* __restrict__ x, const float* __restrict__ Wn,
    const float* __restrict__ attn_src, const float* __restrict__ attn_dst,
    float* __restrict__ h, float* __restrict__ a_src, float* __restrict__ a_dst,
    int n)
{
    __shared__ float Ws[64][64];   // W[k][col]
    __shared__ float xs[64][64];   // x[r][k]
    const int tid  = threadIdx.x;
    const int row0 = blockIdx.x * 64;

    // stage W: 1024 float4, 4 per thread
    const float4* Wn4 = (const float4*)Wn;
    #pragma unroll
    for (int i = tid; i < 1024; i += 256) {
        float4 v = Wn4[i];
        *(float4*)&Ws[i >> 4][(i & 15) * 4] = v;
    }
    // stage x rows row0..row0+63
    const float4* x4 = (const float4*)x;
    #pragma unroll
    for (int i = tid; i < 1024; i += 256) {
        int r  = i >> 4;
        int gr = row0 + r;
        float4 v = (gr < n) ? x4[(size_t)gr * 16 + (i & 15)]
                            : make_float4(0.f, 0.f, 0.f, 0.f);
        *(float4*)&xs[r][(i & 15) * 4] = v;
    }
    __syncthreads();

    const int c4 = tid & 15;   // col group
    const int r4 = tid >> 4;   // base row 0..15

    float4 acc0 = make_float4(0.f, 0.f, 0.f, 0.f);
    float4 acc1 = make_float4(0.f, 0.f, 0.f, 0.f);
    float4 acc2 = make_float4(0.f, 0.f, 0.f, 0.f);
    float4 acc3 = make_float4(0.f, 0.f, 0.f, 0.f);

    #pragma unroll 8
    for (int k = 0; k < 64; ++k) {
        float4 w = *(const float4*)&Ws[k][c4 * 4];
        float x0 = xs[r4     ][k];
        float x1 = xs[r4 + 16][k];
        float x2 = xs[r4 + 32][k];
        float x3 = xs[r4 + 48][k];
        acc0.x += x0 * w.x; acc0.y += x0 * w.y; acc0.z += x0 * w.z; acc0.w += x0 * w.w;
        acc1.x += x1 * w.x; acc1.y += x1 * w.y; acc1.z += x1 * w.z; acc1.w += x1 * w.w;
        acc2.x += x2 * w.x; acc2.y += x2 * w.y; acc2.z += x2 * w.z; acc2.w += x2 * w.w;
        acc3.x += x3 * w.x; acc3.y += x3 * w.y; acc3.z += x3 * w.z; acc3.w += x3 * w.w;
    }

    // attention projection weights for this thread's 4 columns
    const float4 asw = *(const float4*)&attn_src[c4 * 4];
    const float4 adw = *(const float4*)&attn_dst[c4 * 4];
    const int hh = c4 >> 2;                 // head of this col group
    const bool writer = (c4 & 3) == 0;

    float4 accs[4] = {acc0, acc1, acc2, acc3};
    #pragma unroll
    for (int j = 0; j < 4; ++j) {
        int gr = row0 + r4 + 16 * j;
        if (gr < n) {
            *(float4*)&h[(size_t)gr * 64 + c4 * 4] = accs[j];
            float ps = accs[j].x * asw.x + accs[j].y * asw.y +
                       accs[j].z * asw.z + accs[j].w * asw.w;
            float pd = accs[j].x * adw.x + accs[j].y * adw.y +
                       accs[j].z * adw.z + accs[j].w * adw.w;
            ps += __shfl_xor(ps, 1, 64); ps += __shfl_xor(ps, 2, 64);
            pd += __shfl_xor(pd, 1, 64); pd += __shfl_xor(pd, 2, 64);
            if (writer) {
                a_src[(size_t)gr * 4 + hh] = ps;
                a_dst[(size_t)gr * 4 + hh] = pd;
            }
        } else {
            // keep shfl partners converged (values unused)
            float ps = 0.f, pd = 0.f;
            ps += __shfl_xor(ps, 1, 64); ps += __shfl_xor(ps, 2, 64);
            pd += __shfl_xor(pd, 1, 64); pd += __shfl_xor(pd, 2, 64);
        }
    }
}

// ---------------------------------------------------------------------------
// Kernel 2: degree histogram over dst (padded counters, 1 per 64B line).
// ---------------------------------------------------------------------------
__global__ __launch_bounds__(256) void k_hist(
    const int* __restrict__ dst, int* __restrict__ degp, int E)
{
    int e = blockIdx.x * 256 + threadIdx.x;
    if (e < E) atomicAdd(&degp[(size_t)dst[e] * PAD], 1);
}

// ---------------------------------------------------------------------------
// Scan: exclusive prefix sum of degp (strided) -> row_start (dense) +
// cursorp (strided copy).
// ---------------------------------------------------------------------------
__global__ __launch_bounds__(256) void k_scan_reduce(
    const int* __restrict__ degp, int* __restrict__ partials, int n)
{
    const int t = threadIdx.x;
    int idx = blockIdx.x * 1024 + t * 4;
    int s = 0;
    #pragma unroll
    for (int k = 0; k < 4; ++k) { int i = idx + k; if (i < n) s += degp[(size_t)i * PAD]; }
    #pragma unroll
    for (int off = 32; off; off >>= 1) s += __shfl_xor(s, off, 64);
    __shared__ int wsum[4];
    if ((t & 63) == 0) wsum[t >> 6] = s;
    __syncthreads();
    if (t == 0) partials[blockIdx.x] = wsum[0] + wsum[1] + wsum[2] + wsum[3];
}

__global__ void k_scan_partials(int* __restrict__ partials, int nb)
{
    int lane = threadIdx.x;
    int i0 = 2 * lane, i1 = 2 * lane + 1;
    int v0 = (i0 < nb) ? partials[i0] : 0;
    int v1 = (i1 < nb) ? partials[i1] : 0;
    int s = v0 + v1;
    int incl = s;
    #pragma unroll
    for (int off = 1; off < 64; off <<= 1) {
        int u = __shfl_up(incl, off, 64);
        if (lane >= off) incl += u;
    }
    int excl = incl - s;
    if (i0 < nb) partials[i0] = excl;
    if (i1 < nb) partials[i1] = excl + v0;
}

__global__ __launch_bounds__(256) void k_scan_final(
    const int* __restrict__ degp, const int* __restrict__ partials,
    int* __restrict__ row_start, int* __restrict__ cursorp, int n)
{
    const int t = threadIdx.x;
    const int lane = t & 63, wid = t >> 6;
    int idx = blockIdx.x * 1024 + t * 4;
    int d0 = (idx     < n) ? degp[(size_t)(idx    ) * PAD] : 0;
    int d1 = (idx + 1 < n) ? degp[(size_t)(idx + 1) * PAD] : 0;
    int d2 = (idx + 2 < n) ? degp[(size_t)(idx + 2) * PAD] : 0;
    int d3 = (idx + 3 < n) ? degp[(size_t)(idx + 3) * PAD] : 0;
    int s = d0 + d1 + d2 + d3;
    int incl = s;
    #pragma unroll
    for (int off = 1; off < 64; off <<= 1) {
        int u = __shfl_up(incl, off, 64);
        if (lane >= off) incl += u;
    }
    __shared__ int wsum[4];
    if (lane == 63) wsum[wid] = incl;
    __syncthreads();
    int woff = 0;
    for (int i = 0; i < wid; ++i) woff += wsum[i];
    int p = partials[blockIdx.x] + woff + (incl - s);
    if (idx     < n) { row_start[idx    ] = p; cursorp[(size_t)(idx    ) * PAD] = p; } p += d0;
    if (idx + 1 < n) { row_start[idx + 1] = p; cursorp[(size_t)(idx + 1) * PAD] = p; } p += d1;
    if (idx + 2 < n) { row_start[idx + 2] = p; cursorp[(size_t)(idx + 2) * PAD] = p; } p += d2;
    if (idx + 3 < n) { row_start[idx + 3] = p; cursorp[(size_t)(idx + 3) * PAD] = p; }
}

// ---------------------------------------------------------------------------
// Kernel 3: CSR build. Record: int4 { src, f16x2(as0+esc0, as1+esc1),
// f16x2(as2+esc2, as3+esc3), 0 }. Atomic issued FIRST (latency overlapped
// with a_src gather + esc math); padded cursor kills line contention.
// ---------------------------------------------------------------------------
__global__ __launch_bounds__(256) void k_perm_build(
    const int* __restrict__ src, const int* __restrict__ dst,
    const float* __restrict__ ea, const float* __restrict__ We,
    const float* __restrict__ a_src,
    int* __restrict__ cursorp, int4* __restrict__ csr, int E)
{
    __shared__ float Wes[64];   // W_edge [16][4]
    const int tid = threadIdx.x;
    if (tid < 64) Wes[tid] = We[tid];
    __syncthreads();

    int e = blockIdx.x * 256 + tid;
    if (e >= E) return;

    int d = dst[e];
    int pos = atomicAdd(&cursorp[(size_t)d * PAD], 1);   // issue early
    int s = src[e];
    float4 as4 = *(const float4*)(a_src + (size_t)s * 4); // L2-resident gather

    const float4* ea4 = (const float4*)(ea + (size_t)e * 16);
    float4 v0 = ea4[0], v1 = ea4[1], v2 = ea4[2], v3 = ea4[3];
    float eav[16] = {v0.x, v0.y, v0.z, v0.w, v1.x, v1.y, v1.z, v1.w,
                     v2.x, v2.y, v2.z, v2.w, v3.x, v3.y, v3.z, v3.w};
    float esc[H] = {0.f, 0.f, 0.f, 0.f};
    #pragma unroll
    for (int k = 0; k < 16; ++k) {
        #pragma unroll
        for (int hh = 0; hh < H; ++hh) esc[hh] += eav[k] * Wes[k * 4 + hh];
    }

    __half2 p01 = __floats2half2_rn(as4.x + esc[0], as4.y + esc[1]);
    __half2 p23 = __floats2half2_rn(as4.z + esc[2], as4.w + esc[3]);
    int y = *reinterpret_cast<int*>(&p01);
    int z = *reinterpret_cast<int*>(&p23);

    csr[pos] = make_int4(s, y, z, 0);
}

// ---------------------------------------------------------------------------
// Kernel 4: wave-per-node aggregation + residual + LayerNorm.
// Record holds a_src[s]+esc; a_dst read once per node. No max tracking
// (exp(a) directly — differs from reference by <=1e-8 relative).
// Per edge: 3 shfl broadcasts + add + lrelu + exp + 2 fma + coalesced gather.
// ---------------------------------------------------------------------------
__global__ __launch_bounds__(256) void k_aggregate_ln(
    const int* __restrict__ row_start, const int* __restrict__ degp,
    const int4* __restrict__ csr, const float* __restrict__ h,
    const float* __restrict__ a_dst,
    const float* __restrict__ gamma, const float* __restrict__ beta,
    float* __restrict__ out, int n)
{
    int gid  = blockIdx.x * 256 + threadIdx.x;
    int node = gid >> 6;
    int lane = gid & 63;
    if (node >= n) return;
    const int hh   = lane >> 4;
    const int hilo = hh & 1;

    const int rs = row_start[node];
    const int dg = degp[(size_t)node * PAD];

    const float h_node = h[(size_t)node * 64 + lane];
    float4 ad4 = *(const float4*)(a_dst + (size_t)node * 4);
    const float ad = (hh == 0) ? ad4.x : (hh == 1) ? ad4.y : (hh == 2) ? ad4.z : ad4.w;

    float sum = 0.f, accv = 0.f;

#define PROC_EDGE(HV, YW, ZW)                                            \
    {                                                                    \
        int w_ = (hh < 2) ? (YW) : (ZW);                                 \
        float2 f2_ = __half22float2(*reinterpret_cast<__half2*>(&w_));   \
        float a_ = (hilo ? f2_.y : f2_.x) + ad;                          \
        a_ = (a_ >= 0.f) ? a_ : NEG_SLOPE * a_;                          \
        float w2_ = __expf(a_);                                          \
        sum  += w2_;                                                     \
        accv += w2_ * (HV);                                              \
    }

    for (int base = 0; base < dg; base += 64) {
        int cnt = min(64, dg - base);
        int4 myc = (base + lane < dg) ? csr[(size_t)rs + base + lane]
                                      : make_int4(0, 0, 0, 0);
        int i = 0;
        for (; i + 4 <= cnt; i += 4) {
            int s0 = __shfl(myc.x, i + 0, 64);
            int s1 = __shfl(myc.x, i + 1, 64);
            int s2 = __shfl(myc.x, i + 2, 64);
            int s3 = __shfl(myc.x, i + 3, 64);
            int y0 = __shfl(myc.y, i + 0, 64), z0 = __shfl(myc.z, i + 0, 64);
            int y1 = __shfl(myc.y, i + 1, 64), z1 = __shfl(myc.z, i + 1, 64);
            int y2 = __shfl(myc.y, i + 2, 64), z2 = __shfl(myc.z, i + 2, 64);
            int y3 = __shfl(myc.y, i + 3, 64), z3 = __shfl(myc.z, i + 3, 64);
            float hv0 = h[(size_t)s0 * 64 + lane];
            float hv1 = h[(size_t)s1 * 64 + lane];
            float hv2 = h[(size_t)s2 * 64 + lane];
            float hv3 = h[(size_t)s3 * 64 + lane];
            PROC_EDGE(hv0, y0, z0);
            PROC_EDGE(hv1, y1, z1);
            PROC_EDGE(hv2, y2, z2);
            PROC_EDGE(hv3, y3, z3);
        }
        for (; i < cnt; ++i) {
            int s0 = __shfl(myc.x, i, 64);
            int y0 = __shfl(myc.y, i, 64);
            int z0 = __shfl(myc.z, i, 64);
            float hv0 = h[(size_t)s0 * 64 + lane];
            PROC_EDGE(hv0, y0, z0);
        }
    }
#undef PROC_EDGE

    float y = accv / (sum + EPS_SM) + h_node;

    // LayerNorm across the 64 lanes
    float t1 = y;
    #pragma unroll
    for (int off = 32; off; off >>= 1) t1 += __shfl_xor(t1, off, 64);
    float mu = t1 * (1.f / 64.f);
    float dv = y - mu;
    float vs = dv * dv;
    #pragma unroll
    for (int off = 32; off; off >>= 1) vs += __shfl_xor(vs, off, 64);
    float var = vs * (1.f / 64.f);
    out[(size_t)node * 64 + lane] = dv * rsqrtf(var + EPS_LN) * gamma[lane] + beta[lane];
}

// ---------------------------------------------------------------------------
extern "C" void kernel_launch(void* const* d_in, const int* in_sizes, int n_in,
                              void* d_out, int out_size, void* d_ws, size_t ws_size,
                              hipStream_t stream)
{
    const float* x     = (const float*)d_in[0];
    const int*   ei    = (const int*)  d_in[1];
    const float* ea    = (const float*)d_in[2];
    const float* Wn    = (const float*)d_in[3];
    const float* We    = (const float*)d_in[4];
    const float* asrcW = (const float*)d_in[5];
    const float* adstW = (const float*)d_in[6];
    const float* gamma = (const float*)d_in[7];
    const float* beta  = (const float*)d_in[8];
    float* out = (float*)d_out;

    const int n = in_sizes[0] / 64;
    const int E = in_sizes[1] / 2;
    const int* src = ei;
    const int* dst = ei + E;
    const int nb = (n + 1023) / 1024;

    float* ws = (float*)d_ws;
    size_t off = 0;
    float* h_    = ws + off; off += (size_t)n * 64;      // 16B-aligned
    float* a_src = ws + off; off += (size_t)n * 4;
    float* a_dst = ws + off; off += (size_t)n * 4;
    int4* csr    = (int4*)(ws + off); off += (size_t)E * 4;
    int* ibase     = (int*)(ws + off);
    int* degp      = ibase;                          // n*PAD
    int* cursorp   = ibase + (size_t)n * PAD;        // n*PAD
    int* row_start = ibase + 2 * (size_t)n * PAD;    // n
    int* partials  = ibase + 2 * (size_t)n * PAD + n; // nb

    hipMemsetAsync(degp, 0, (size_t)n * PAD * sizeof(int), stream);

    k_node<<<(n + 63) / 64, 256, 0, stream>>>(x, Wn, asrcW, adstW, h_, a_src, a_dst, n);
    k_hist<<<(E + 255) / 256, 256, 0, stream>>>(dst, degp, E);
    k_scan_reduce<<<nb, 256, 0, stream>>>(degp, partials, n);
    k_scan_partials<<<1, 64, 0, stream>>>(partials, nb);
    k_scan_final<<<nb, 256, 0, stream>>>(degp, partials, row_start, cursorp, n);
    k_perm_build<<<(E + 255) / 256, 256, 0, stream>>>(src, dst, ea, We, a_src,
                                                      cursorp, csr, E);
    k_aggregate_ln<<<((size_t)n * 64 + 255) / 256, 256, 0, stream>>>(
        row_start, degp, csr, h_, a_dst, gamma, beta, out, n);
}